// Round 6
// baseline (396.971 us; speedup 1.0000x reference)
//
#include <hip/hip_runtime.h>

// Problem constants (match reference)
constexpr int Bx = 64;
constexpr int Lx = 1024;
constexpr int Dx = 1024;
constexpr int Sx = 32;

constexpr int LQ    = 256;            // tokens per scatter block
constexpr int NQ    = Lx / LQ;        // 4 l-quarters
constexpr int NSCAT = Bx * NQ;        // 256 blocks = 1/CU
constexpr int PREF  = 8;              // rolling loads in flight per wave

// ---------------------------------------------------------------------------
// Kernel 0: per-batch label histogram -> wcnt[b][s]
// ---------------------------------------------------------------------------
__global__ __launch_bounds__(1024) void hist_kernel(
    const int* __restrict__ attrs, int* __restrict__ wcnt)
{
    __shared__ int hist[Sx + 1];
    const int b = blockIdx.x, tid = threadIdx.x;
    if (tid <= Sx) hist[tid] = 0;
    __syncthreads();
    atomicAdd(&hist[attrs[b * Lx + tid]], 1);
    __syncthreads();
    if (tid >= 1 && tid <= Sx) wcnt[b * Sx + (tid - 1)] = hist[tid];
}

// ---------------------------------------------------------------------------
// Kernel 1: segment-sum scatter, pure sequential streaming.
//  Block = (batch b, 256-token range): streams a CONTIGUOUS 1 MB region of
//  text front-to-back. 256 threads; thread owns 4 fixed cols -> each wave
//  float4 load is 1 KB contiguous (the m13 6.3 TB/s copy pattern; rounds
//  2-5 never had this: gather was random 1KB, R5 was 64B-granule strided).
//  All lanes process the same token -> label is wave-uniform ->
//  readfirstlane + scalar 33-way switch accumulating into float4 acc[32]
//  held in VGPRs (constant indices only -> no scratch). No LDS/MFMA in the
//  hot loop. Rolling 8-deep prefetch, slots resolved at compile time.
//  Epilogue: acc -> pseg[bid][s][col] (full overwrite, no init needed).
// ---------------------------------------------------------------------------
__global__ __launch_bounds__(256, 1) void seg_scatter_kernel(
    const float* __restrict__ text,    // [B][L][D]
    const int*   __restrict__ attrs,   // [B][L]
    float* __restrict__ pseg)          // [NSCAT][S][D]
{
    __shared__ int attrs_lds[LQ];

    const int tid = threadIdx.x;
    const int bid = blockIdx.x;
    const int b   = bid >> 2;
    const int q   = bid & 3;
    const int l0  = q * LQ;
    const int col = tid * 4;           // thread's 4 columns

    if (tid < LQ) attrs_lds[tid] = attrs[b * Lx + l0 + tid];
    __syncthreads();

    const float* __restrict__ tp =
        text + ((size_t)b * Lx + l0) * Dx + col;

    float4 acc[Sx];
    #pragma unroll
    for (int s = 0; s < Sx; ++s) acc[s] = make_float4(0.f, 0.f, 0.f, 0.f);

    float4 buf[PREF];
    #pragma unroll
    for (int j = 0; j < PREF; ++j)
        buf[j] = *(const float4*)(tp + (size_t)j * Dx);

#define ACC_CASE(K) case K:                                   \
        acc[K-1].x += v.x; acc[K-1].y += v.y;                 \
        acc[K-1].z += v.z; acc[K-1].w += v.w; break;

    for (int i0 = 0; i0 < LQ; i0 += PREF) {
        #pragma unroll
        for (int j = 0; j < PREF; ++j) {          // j literal -> buf[j] static
            const float4 v = buf[j];
            const int    i = i0 + j;
            if (i + PREF < LQ)
                buf[j] = *(const float4*)(tp + (size_t)(i + PREF) * Dx);
            const int sa = __builtin_amdgcn_readfirstlane(attrs_lds[i]);
            switch (sa) {                          // wave-uniform scalar jump
                ACC_CASE(1)  ACC_CASE(2)  ACC_CASE(3)  ACC_CASE(4)
                ACC_CASE(5)  ACC_CASE(6)  ACC_CASE(7)  ACC_CASE(8)
                ACC_CASE(9)  ACC_CASE(10) ACC_CASE(11) ACC_CASE(12)
                ACC_CASE(13) ACC_CASE(14) ACC_CASE(15) ACC_CASE(16)
                ACC_CASE(17) ACC_CASE(18) ACC_CASE(19) ACC_CASE(20)
                ACC_CASE(21) ACC_CASE(22) ACC_CASE(23) ACC_CASE(24)
                ACC_CASE(25) ACC_CASE(26) ACC_CASE(27) ACC_CASE(28)
                ACC_CASE(29) ACC_CASE(30) ACC_CASE(31) ACC_CASE(32)
                default: break;                    // label 0: ignore
            }
        }
    }
#undef ACC_CASE

    // store partials: 32 coalesced 1 KB wave-stores
    float* __restrict__ op = pseg + (size_t)bid * Sx * Dx + col;
    #pragma unroll
    for (int s = 0; s < Sx; ++s)
        *(float4*)(op + (size_t)s * Dx) = acc[s];
}

// ---------------------------------------------------------------------------
// Kernel 2: per (b,s): fold 4 l-quarter partials, dot with Vgs, norms.
// ---------------------------------------------------------------------------
__global__ __launch_bounds__(256) void reduce_kernel(
    const float* __restrict__ pseg,    // [NSCAT][S][D]
    const float* __restrict__ vgs,     // [B][S][D]
    float* __restrict__ pnum,          // [B*S]
    float* __restrict__ pns2,          // [B*S]
    float* __restrict__ pnv2)          // [B*S]
{
    const int tid = threadIdx.x;
    const int bid = blockIdx.x;        // = b*Sx + s
    const int b   = bid >> 5;
    const int s   = bid & 31;
    const int col = tid * 4;

    float4 seg = make_float4(0.f, 0.f, 0.f, 0.f);
    #pragma unroll
    for (int q = 0; q < NQ; ++q) {
        const float4 p = *(const float4*)(
            pseg + ((size_t)((b * NQ + q) * Sx + s)) * Dx + col);
        seg.x += p.x; seg.y += p.y; seg.z += p.z; seg.w += p.w;
    }
    const float4 vv = *(const float4*)(vgs + (size_t)bid * Dx + col);

    float pn = seg.x * vv.x + seg.y * vv.y + seg.z * vv.z + seg.w * vv.w;
    float ps = seg.x * seg.x + seg.y * seg.y + seg.z * seg.z + seg.w * seg.w;
    float pv = vv.x * vv.x + vv.y * vv.y + vv.z * vv.z + vv.w * vv.w;

    #pragma unroll
    for (int off = 32; off > 0; off >>= 1) {
        pn += __shfl_xor(pn, off, 64);
        ps += __shfl_xor(ps, off, 64);
        pv += __shfl_xor(pv, off, 64);
    }
    __shared__ float red[3][4];
    if ((tid & 63) == 0) {
        red[0][tid >> 6] = pn; red[1][tid >> 6] = ps; red[2][tid >> 6] = pv;
    }
    __syncthreads();
    if (tid == 0) {
        pnum[bid] = red[0][0] + red[0][1] + red[0][2] + red[0][3];
        pns2[bid] = red[1][0] + red[1][1] + red[1][2] + red[1][3];
        pnv2[bid] = red[2][0] + red[2][1] + red[2][2] + red[2][3];
    }
}

// ---------------------------------------------------------------------------
// Kernel 3: torch cosine eps semantics, scalar loss.
//   cos = num / max(||V|| * ||seg_sum||, eps*cnt)
// ---------------------------------------------------------------------------
__global__ __launch_bounds__(256) void finalize_kernel(
    const float* __restrict__ pnum, const float* __restrict__ pns2,
    const float* __restrict__ pnv2, const int* __restrict__ wcnt,
    float* __restrict__ out)
{
    const int tid = threadIdx.x;
    float lsum = 0.0f;
    #pragma unroll
    for (int k = 0; k < (Bx * Sx) / 256; ++k) {
        const int p = k * 256 + tid;
        const float cnt   = (float)wcnt[p];
        const float denom = fmaxf(sqrtf(pnv2[p]) * sqrtf(pns2[p]),
                                  1e-8f * cnt);
        lsum += pnum[p] / denom;
    }
    #pragma unroll
    for (int off = 32; off > 0; off >>= 1) lsum += __shfl_xor(lsum, off, 64);

    __shared__ float red[4];
    if ((tid & 63) == 0) red[tid >> 6] = lsum;
    __syncthreads();
    if (tid == 0) {
        const float total = red[0] + red[1] + red[2] + red[3];
        out[0] = 1.0f - total * (1.0f / (float)(Bx * Sx));
    }
}

// ---------------------------------------------------------------------------
extern "C" void kernel_launch(void* const* d_in, const int* in_sizes, int n_in,
                              void* d_out, int out_size, void* d_ws, size_t ws_size,
                              hipStream_t stream) {
    const int*   attrs = (const int*)d_in[0];
    const float* text  = (const float*)d_in[1];
    const float* vgs   = (const float*)d_in[2];
    float* out = (float*)d_out;

    float* pseg = (float*)d_ws;                      // 256*32*1024 f32 = 32 MB
    float* pnum = pseg + (size_t)NSCAT * Sx * Dx;    // 8 KB
    float* pns2 = pnum + Bx * Sx;                    // 8 KB
    float* pnv2 = pns2 + Bx * Sx;                    // 8 KB
    int*   wcnt = (int*)(pnv2 + Bx * Sx);            // 8 KB

    hist_kernel<<<Bx, 1024, 0, stream>>>(attrs, wcnt);
    seg_scatter_kernel<<<NSCAT, 256, 0, stream>>>(text, attrs, pseg);
    reduce_kernel<<<Bx * Sx, 256, 0, stream>>>(pseg, vgs, pnum, pns2, pnv2);
    finalize_kernel<<<1, 256, 0, stream>>>(pnum, pns2, pnv2, wcnt, out);
}